// Round 21
// baseline (395.635 us; speedup 1.0000x reference)
//
#include <hip/hip_runtime.h>
#include <hip/hip_bf16.h>

// ---- problem constants ----
#define B_    1024
#define D_    384
#define Q_    65536
#define N_    66560            // B_ + Q_
#define TOPK_ 128

#define NBIN_ 4096             // histogram bins = key >> 4
#define CAP_  2048             // fallback candidate cap
#define SRANK_ 24              // sample rank (of 4096) for fine-bin threshold
#define SLOTS_ 17              // 16 real + 1 trash slot per thread

typedef __bf16 bf16x8 __attribute__((ext_vector_type(8)));
typedef float  f32x4  __attribute__((ext_vector_type(4)));
typedef unsigned short u16;
typedef u16 u16x8 __attribute__((ext_vector_type(8)));

// RNE float -> bf16 (bit-level)
__device__ __forceinline__ unsigned short f2bf(float x) {
  unsigned int u = __float_as_uint(x);
  unsigned int r = (u + 0x7fffu + ((u >> 16) & 1u)) >> 16;
  return (unsigned short)r;
}

__device__ __forceinline__ void gld_lds16(const void* g, void* l) {
  __builtin_amdgcn_global_load_lds(
      (__attribute__((address_space(1))) void*)(g),
      (__attribute__((address_space(3))) void*)(l), 16, 0, 0);
}

__device__ __forceinline__ void wait_vmcnt(int n) {
  switch (n) {
    case 4:  asm volatile("s_waitcnt vmcnt(4)"  ::: "memory"); break;
    default: asm volatile("s_waitcnt vmcnt(0)"  ::: "memory"); break;
  }
}

// monotone key <-> bf16 bits
__device__ __forceinline__ unsigned int bf2key(unsigned int u) {
  return u ^ ((u & 0x8000u) ? 0xFFFFu : 0x8000u);
}
__device__ __forceinline__ float key2val(unsigned int k) {
  unsigned int u = (k & 0x8000u) ? (k ^ 0x8000u) : (~k & 0xFFFFu);
  return __uint_as_float(u << 16);
}

// ---------------------------------------------------------------------------
// Normalize rgb/ir feats -> bf16 z (Ball role) and bf16 z/temp (A role).
// ---------------------------------------------------------------------------
__global__ __launch_bounds__(64) void k_normalize(
    const float* __restrict__ rgb, const float* __restrict__ ir,
    const int* __restrict__ ep,
    u16* __restrict__ zrA, u16* __restrict__ ziA,
    u16* __restrict__ zrU, u16* __restrict__ ziU)
{
  int r = blockIdx.x & (B_ - 1);
  bool isIr = blockIdx.x >= B_;
  const float* src = (isIr ? ir : rgb) + (size_t)r * D_;
  u16* dA = (isIr ? ziA : zrA) + (size_t)r * D_;
  u16* dU = (isIr ? ziU : zrU) + (size_t)r * D_;
  int t = threadIdx.x;
  float x[6]; float ss = 0.f;
  #pragma unroll
  for (int k = 0; k < 6; ++k) { x[k] = src[t + 64*k]; ss += x[k]*x[k]; }
  #pragma unroll
  for (int off = 32; off > 0; off >>= 1) ss += __shfl_down(ss, off);
  ss = __shfl(ss, 0);
  float inv = 1.0f / fmaxf(sqrtf(ss), 1e-12f);

  int e = ep[0];
  float temp;
  if (e >= 10) temp = 0.05f;
  else {
    float p = (float)e * 0.1f;
    temp = 0.05f + 0.075f * (1.0f + cosf(3.14159265358979323846f * p));
  }
  float itemp = 1.0f / temp;

  #pragma unroll
  for (int k = 0; k < 6; ++k) {
    float z = x[k] * inv;
    dU[t + 64*k] = f2bf(z);
    dA[t + 64*k] = f2bf(z * itemp);
  }
}

// ---------------------------------------------------------------------------
// Build Ball bf16 [N_][D_] = [z_other (bf16 copy) ; queue (f32->bf16)]
// ---------------------------------------------------------------------------
__global__ __launch_bounds__(256) void k_build_ball(
    const u16* __restrict__ zU, const float* __restrict__ queue,
    u16* __restrict__ ball)
{
  size_t i = ((size_t)blockIdx.x * 256 + threadIdx.x) * 8;
  const size_t zElems = (size_t)B_ * D_;
  if (i < zElems) {
    *(uint4*)(ball + i) = *(const uint4*)(zU + i);
  } else {
    const float* q = queue + (i - zElems);
    float4 a = *(const float4*)q;
    float4 b = *(const float4*)(q + 4);
    u16x8 o;
    o[0] = f2bf(a.x); o[1] = f2bf(a.y); o[2] = f2bf(a.z); o[3] = f2bf(a.w);
    o[4] = f2bf(b.x); o[5] = f2bf(b.y); o[6] = f2bf(b.z); o[7] = f2bf(b.w);
    *(u16x8*)(ball + i) = o;
  }
}

// ---------------------------------------------------------------------------
// bf16 MFMA GEMM -> bf16 logits slab (r15 K-loop, best: 78us).
// NEW: epilogue also accumulates per-row partial expsum (f32 acc values,
// post-diag-poison) -> butterfly over the 16 col-lanes -> one global
// atomicAdd per row per wave into rowsum[B] (zeroed per call by host).
// ---------------------------------------------------------------------------
#define BK_ 32
#define NSTEP_ 12              // D_ / BK_
__global__ __launch_bounds__(256, 3) void k_gemm(
    const u16* __restrict__ A,     // [B_][D_] scaled bf16
    const u16* __restrict__ ball,  // [N_][D_] bf16
    u16* __restrict__ C,           // [SR][N_] bf16 logits
    float* __restrict__ diag,      // [B_]
    float* __restrict__ rsum,      // [B_] per-direction expsum accumulator
    int r0, int mtiles)
{
  __shared__ __align__(16) unsigned char smem[49152];  // 3 x (8KB A + 8KB B)
  u16* Ct = (u16*)smem;          // epilogue bounce [128][136] (34.8 KB)

  int bid = blockIdx.x;
  int nwg = gridDim.x;
  int cpx = nwg >> 3;
  int wgid = (bid & 7) * cpx + (bid >> 3);
  int nt = wgid / mtiles;
  int mt = wgid - nt * mtiles;

  const int tid  = threadIdx.x;
  const int wave = tid >> 6, lane = tid & 63;
  const int wm = wave >> 1, wn = wave & 1;
  const int mbase = mt * 128;
  const int nbase = nt * 128;
  const u16* Ab = A    + (size_t)(r0 + mbase) * D_;
  const u16* Bb = ball + (size_t)nbase * D_;

  auto As = [&](int t) -> u16* { return (u16*)(smem + (t % 3) * 16384); };
  auto Bs = [&](int t) -> u16* { return (u16*)(smem + (t % 3) * 16384 + 8192); };
  auto stage = [&](int t) {
    const int ks = t * BK_;
    #pragma unroll
    for (int i = 0; i < 2; ++i) {
      int f = i * 256 + tid;
      int rr = f >> 2, cc = f & 3;
      int koff = (((cc * 16) ^ (((rr >> 1) & 3) << 4)) >> 1);
      gld_lds16(Ab + (size_t)rr * D_ + ks + koff, As(t) + (size_t)f * 8);
      gld_lds16(Bb + (size_t)rr * D_ + ks + koff, Bs(t) + (size_t)f * 8);
    }
  };

  f32x4 acc[4][4];
  #pragma unroll
  for (int m = 0; m < 4; ++m)
    #pragma unroll
    for (int n = 0; n < 4; ++n)
      #pragma unroll
      for (int r = 0; r < 4; ++r) acc[m][n][r] = 0.0f;

  const int lr = lane & 15;
  const int kb = (lane >> 4) * 16;   // byte column within the 64B row

  stage(0); stage(1);                // 8 loads/thread in flight

  #pragma unroll
  for (int t = 0; t < NSTEP_; ++t) {
    wait_vmcnt(t < NSTEP_ - 1 ? 4 : 0);      // tile t landed (t+1 in flight)
    __builtin_amdgcn_s_barrier();            // tile t ready AND all waves done
    __builtin_amdgcn_sched_barrier(0);       //   reading tile t-1

    const u16* Ac = As(t);
    const u16* Bc = Bs(t);
    bf16x8 af[4], bq[4];
    #pragma unroll
    for (int m = 0; m < 4; ++m) {
      int row = wm*64 + m*16 + lr;
      af[m] = *(const bf16x8*)((const char*)Ac + row * 64 + (kb ^ (((row >> 1) & 3) << 4)));
    }
    #pragma unroll
    for (int n = 0; n < 4; ++n) {
      int row = wn*64 + n*16 + lr;
      bq[n] = *(const bf16x8*)((const char*)Bc + row * 64 + (kb ^ (((row >> 1) & 3) << 4)));
    }
    if (t + 2 < NSTEP_) stage(t + 2);        // overwrites buffer (t-1)%3: safe

    #pragma unroll
    for (int m = 0; m < 4; ++m)
      #pragma unroll
      for (int n = 0; n < 4; ++n)
        acc[m][n] = __builtin_amdgcn_mfma_f32_16x16x32_bf16(af[m], bq[n], acc[m][n], 0, 0, 0);

    asm volatile("s_waitcnt lgkmcnt(0)" ::: "memory");  // my ds_reads done
    __builtin_amdgcn_sched_barrier(0);
  }
  __syncthreads();                           // all waves done before smem reuse

  // ---- epilogue: diag + bf16 convert into LDS bounce + partial expsum ----
  // D layout: col = lane&15, row = (lane>>4)*4 + reg.
  const int rowq = (lane >> 4) * 4;
  #pragma unroll
  for (int m = 0; m < 4; ++m) {
    #pragma unroll
    for (int r = 0; r < 4; ++r) {
      int lrow = wm*64 + m*16 + rowq + r;
      int grow = r0 + mbase + lrow;
      float es = 0.f;
      #pragma unroll
      for (int n = 0; n < 4; ++n) {
        int lcol = wn*64 + n*16 + lr;
        int gcol = nbase + lcol;
        float x = acc[m][n][r];
        if (gcol == grow) { diag[grow] = x; x = -60.0f; }
        Ct[lrow * 136 + lcol] = f2bf(x);
        es += __expf(x);
      }
      // butterfly over the 16 col-lanes (lane&15)
      es += __shfl_xor(es, 1);
      es += __shfl_xor(es, 2);
      es += __shfl_xor(es, 4);
      es += __shfl_xor(es, 8);
      if ((lane & 15) == 0) atomicAdd(&rsum[grow], es);
    }
  }
  __syncthreads();

  // ---- coalesced store: 16 threads x 16B = 256B per row ----
  int rrow = tid >> 4;             // 0..15
  int cchunk = (tid & 15) * 8;     // u16 index within row
  #pragma unroll
  for (int pass = 0; pass < 8; ++pass) {
    int row = pass * 16 + rrow;
    u16x8 v = *(const u16x8*)(Ct + row * 136 + cchunk);
    *(u16x8*)(C + (size_t)(mbase + row) * N_ + nbase + cchunk) = v;
  }
}

// ---------------------------------------------------------------------------
// Per-row exact top-128 + loss. SINGLE sweep, no expsum (done in gemm), no
// per-element histogram: hot loop = load + bf2key + branchless slot-write +
// count. Monotonicity: collected keys (bin >= tfine) dominate all others, so
// if total collected >= 128 (and no slot overflow) top-128 is in the slots.
// Boundary resolved exactly from collected keys. Fallback: full 2-sweep.
// ---------------------------------------------------------------------------
__global__ __launch_bounds__(256) void k_select(
    const u16* __restrict__ C, const float* __restrict__ diag,
    const float* __restrict__ rsum,
    float* __restrict__ rowloss, int r0)
{
  __shared__ unsigned int hist[NBIN_];          // 16 KB
  __shared__ u16 keyslots[256 * SLOTS_];        // 8.5 KB
  __shared__ float vals[CAP_];                  // 8 KB (fallback only)
  __shared__ float fred[256];
  __shared__ unsigned int csum[256];
  __shared__ int lcnt[256];
  __shared__ unsigned int subhist[16];
  __shared__ float sh_d2;
  __shared__ int shv[4];                        // 0:bstar 1:above 2:cnt 3:tfine

  const int t = threadIdx.x;
  const int grow = r0 + blockIdx.x;
  const u16x8* p = (const u16x8*)(C + (size_t)blockIdx.x * N_);

  uint4* h4 = (uint4*)hist;
  #pragma unroll
  for (int i = 0; i < 4; ++i) h4[i * 256 + t] = make_uint4(0,0,0,0);
  if (t < 16) subhist[t] = 0;
  if (t == 0) { shv[2] = 0; sh_d2 = 0.f; }
  __syncthreads();

  // ---- sample phase: 4096 values -> fine histogram -> tfine ----
  {
    u16x8 s0 = p[t * 32];
    u16x8 s1 = p[t * 32 + 16];
    #pragma unroll
    for (int e = 0; e < 8; ++e) {
      atomicAdd(&hist[bf2key((unsigned int)(unsigned short)s0[e]) >> 4], 1u);
      atomicAdd(&hist[bf2key((unsigned int)(unsigned short)s1[e]) >> 4], 1u);
    }
  }
  __syncthreads();
  {
    unsigned int S = 0;
    #pragma unroll
    for (int i = 0; i < 16; ++i) S += hist[t * 16 + i];
    csum[t] = S;
    __syncthreads();
    unsigned int a = S;
    #pragma unroll
    for (int s = 1; s < 256; s <<= 1) {
      unsigned int add = (t + s < 256) ? csum[t + s] : 0u;
      __syncthreads();
      a += add; csum[t] = a;
      __syncthreads();
    }
    int above = (t < 255) ? (int)csum[t + 1] : 0;
    if (above < SRANK_ && above + (int)S >= SRANK_) {
      int cum = above;
      #pragma unroll 1
      for (int i = 15; i >= 0; --i) {
        int c = (int)hist[t * 16 + i];
        if (cum + c >= SRANK_) { shv[3] = t * 16 + i; break; }
        cum += c;
      }
    }
  }
  __syncthreads();
  const unsigned int tfine = (unsigned int)shv[3];
  #pragma unroll
  for (int i = 0; i < 4; ++i) h4[i * 256 + t] = make_uint4(0,0,0,0);
  __syncthreads();

  // ---- main sweep: branchless slot collect only (no expsum, no hist) ----
  u16* myslots = keyslots + t * SLOTS_;
  int lc = 0;
  #pragma unroll 1
  for (int base = 0; base < 8192; base += 2048) {
    u16x8 v[8];
    #pragma unroll
    for (int j = 0; j < 8; ++j) v[j] = p[base + j * 256 + t];
    #pragma unroll
    for (int j = 0; j < 8; ++j) {
      #pragma unroll
      for (int e = 0; e < 8; ++e) {
        unsigned int k = bf2key((unsigned int)(unsigned short)v[j][e]);
        myslots[lc < 16 ? lc : 16] = (u16)k;     // unconditional write
        lc += ((k >> 4) >= tfine);               // branchless count
      }
    }
  }
  if (t < 128) {                         // tail: chunks 8192..8319
    u16x8 v = p[8192 + t];
    #pragma unroll
    for (int e = 0; e < 8; ++e) {
      unsigned int k = bf2key((unsigned int)(unsigned short)v[e]);
      myslots[lc < 16 ? lc : 16] = (u16)k;
      lc += ((k >> 4) >= tfine);
    }
  }
  lcnt[t] = lc;
  __syncthreads();

  // ---- total candidate count + overflow check ----
  {
    csum[t] = (unsigned int)lcnt[t];
    __syncthreads();
    #pragma unroll
    for (int s = 128; s > 0; s >>= 1) {
      unsigned int add = (t < s) ? csum[t + s] : 0u;
      __syncthreads();
      if (t < s) csum[t] = csum[t] + add;
      __syncthreads();
    }
  }
  const int cntTot = (int)csum[0];
  int ok_lc = __syncthreads_and(lc <= 16);

  float delta = 0.f;
  if (ok_lc && cntTot >= TOPK_) {
    // ---- fast path: histogram ONLY the candidates (~850 atomics) ----
    #pragma unroll 1
    for (int i = t; i < 256 * 16; i += 256) {
      int ts = i >> 4, sl = i & 15;
      int c = lcnt[ts]; c = c < 16 ? c : 16;
      if (sl < c)
        atomicAdd(&hist[(unsigned int)keyslots[ts * SLOTS_ + sl] >> 4], 1u);
    }
    __syncthreads();
    unsigned int S = 0;
    #pragma unroll
    for (int i = 0; i < 16; ++i) S += hist[t * 16 + i];
    csum[t] = S;
    __syncthreads();
    unsigned int a = S;
    #pragma unroll
    for (int s = 1; s < 256; s <<= 1) {
      unsigned int add = (t + s < 256) ? csum[t + s] : 0u;
      __syncthreads();
      a += add; csum[t] = a;
      __syncthreads();
    }
    int above_chunk = (t < 255) ? (int)csum[t + 1] : 0;
    if (above_chunk < TOPK_ && above_chunk + (int)S >= TOPK_) {
      int cum = above_chunk;
      #pragma unroll 1
      for (int i = 15; i >= 0; --i) {
        int c = (int)hist[t * 16 + i];
        if (cum + c >= TOPK_) { shv[0] = t * 16 + i; shv[1] = cum; break; }
        cum += c;
      }
    }
    __syncthreads();
    const unsigned int bstar = (unsigned int)shv[0];
    const int need0 = TOPK_ - shv[1];
    #pragma unroll 1
    for (int i = t; i < 256 * 16; i += 256) {
      int ts = i >> 4, sl = i & 15;
      int c = lcnt[ts]; c = c < 16 ? c : 16;
      if (sl < c) {
        unsigned int k = (unsigned int)keyslots[ts * SLOTS_ + sl];
        unsigned int bin = k >> 4;
        if (bin > bstar) {
          float v = key2val(k);
          delta += __expf(2.f * v) - __expf(v);
        } else if (bin == bstar) {
          atomicAdd(&subhist[k & 15], 1u);
        }
      }
    }
    __syncthreads();
    if (t == 0) {
      int need = need0; float d2 = 0.f;
      #pragma unroll 1
      for (int sk = 15; sk >= 0 && need > 0; --sk) {
        int c = (int)subhist[sk];
        if (c > 0) {
          int take = c < need ? c : need;
          float v = key2val((bstar << 4) | (unsigned int)sk);
          d2 += (float)take * (__expf(2.f * v) - __expf(v));
          need -= take;
        }
      }
      sh_d2 = d2;
    }
  } else {
    // ---- exact fallback: full 2-sweep (hist sweep + collect sweep) ----
    #pragma unroll 1
    for (int base = 0; base < 8192; base += 2048) {
      u16x8 v[8];
      #pragma unroll
      for (int j = 0; j < 8; ++j) v[j] = p[base + j * 256 + t];
      #pragma unroll
      for (int j = 0; j < 8; ++j)
        #pragma unroll
        for (int e = 0; e < 8; ++e)
          atomicAdd(&hist[bf2key((unsigned int)(unsigned short)v[j][e]) >> 4], 1u);
    }
    if (t < 128) {
      u16x8 v = p[8192 + t];
      #pragma unroll
      for (int e = 0; e < 8; ++e)
        atomicAdd(&hist[bf2key((unsigned int)(unsigned short)v[e]) >> 4], 1u);
    }
    __syncthreads();
    unsigned int S = 0;
    #pragma unroll
    for (int i = 0; i < 16; ++i) S += hist[t * 16 + i];
    csum[t] = S;
    __syncthreads();
    unsigned int a = S;
    #pragma unroll
    for (int s = 1; s < 256; s <<= 1) {
      unsigned int add = (t + s < 256) ? csum[t + s] : 0u;
      __syncthreads();
      a += add; csum[t] = a;
      __syncthreads();
    }
    int above_chunk = (t < 255) ? (int)csum[t + 1] : 0;
    if (above_chunk < TOPK_ && above_chunk + (int)S >= TOPK_) {
      int cum = above_chunk;
      #pragma unroll 1
      for (int i = 15; i >= 0; --i) {
        int c = (int)hist[t * 16 + i];
        if (cum + c >= TOPK_) { shv[0] = t * 16 + i; shv[1] = cum; break; }
        cum += c;
      }
    }
    __syncthreads();
    const unsigned int bstar = (unsigned int)shv[0];
    const int need0 = TOPK_ - shv[1];
    #pragma unroll 1
    for (int base = 0; base < 8192; base += 2048) {
      u16x8 v[8];
      #pragma unroll
      for (int j = 0; j < 8; ++j) v[j] = p[base + j * 256 + t];
      #pragma unroll
      for (int j = 0; j < 8; ++j) {
        #pragma unroll
        for (int e = 0; e < 8; ++e) {
          unsigned int u = (unsigned int)(unsigned short)v[j][e];
          unsigned int bin = bf2key(u) >> 4;
          if (bin >= bstar) {
            float val = __uint_as_float(u << 16);
            if (bin > bstar) delta += __expf(2.f * val) - __expf(val);
            else { int s = atomicAdd(&shv[2], 1); if (s < CAP_) vals[s] = val; }
          }
        }
      }
    }
    if (t < 128) {
      u16x8 v = p[8192 + t];
      #pragma unroll
      for (int e = 0; e < 8; ++e) {
        unsigned int u = (unsigned int)(unsigned short)v[e];
        unsigned int bin = bf2key(u) >> 4;
        if (bin >= bstar) {
          float val = __uint_as_float(u << 16);
          if (bin > bstar) delta += __expf(2.f * val) - __expf(val);
          else { int s = atomicAdd(&shv[2], 1); if (s < CAP_) vals[s] = val; }
        }
      }
    }
    __syncthreads();
    int C2 = shv[2] < CAP_ ? shv[2] : CAP_;
    for (int i = t; i < C2; i += 256) {
      float v = vals[i];
      int g = 0;
      for (int k = 0; k < C2; ++k)
        g += (vals[k] > v) || (vals[k] == v && k < i);
      if (g < need0) delta += __expf(2.f * v) - __expf(v);
    }
  }

  fred[t] = delta;
  __syncthreads();
  #pragma unroll
  for (int s = 128; s > 0; s >>= 1) { if (t < s) fred[t] += fred[t + s]; __syncthreads(); }

  if (t == 0) {
    float d = diag[grow];
    rowloss[grow] = logf(rsum[grow] + fred[0] + sh_d2 + __expf(d)) - d;
  }
}

__global__ __launch_bounds__(256) void k_final(
    const float* __restrict__ rowloss, float* __restrict__ out)
{
  __shared__ float red[256];
  int t = threadIdx.x;
  float s = 0.f;
  for (int i = t; i < 2 * B_; i += 256) s += rowloss[i];
  red[t] = s;
  __syncthreads();
  for (int k = 128; k > 0; k >>= 1) { if (t < k) red[t] += red[t + k]; __syncthreads(); }
  if (t == 0) out[0] = red[0] * (1.0f / (2.0f * B_));
}

// ---------------------------------------------------------------------------
extern "C" void kernel_launch(void* const* d_in, const int* in_sizes, int n_in,
                              void* d_out, int out_size, void* d_ws, size_t ws_size,
                              hipStream_t stream)
{
  const float* rgb_feat = (const float*)d_in[0];
  const float* ir_feat  = (const float*)d_in[1];
  const float* rgb_q    = (const float*)d_in[2];
  const float* ir_q     = (const float*)d_in[3];
  const int*   epoch    = (const int*)d_in[4];

  char* ws = (char*)d_ws;
  size_t off = 0;
  auto alloc = [&](size_t bytes) -> char* {
    char* p = ws + off;
    off = (off + bytes + 255) & ~(size_t)255;
    return p;
  };

  u16* zrA = (u16*)alloc((size_t)B_ * D_ * 2);
  u16* ziA = (u16*)alloc((size_t)B_ * D_ * 2);
  u16* zrU = (u16*)alloc((size_t)B_ * D_ * 2);
  u16* ziU = (u16*)alloc((size_t)B_ * D_ * 2);
  float* diag    = (float*)alloc((size_t)2 * B_ * 4);
  float* rowloss = (float*)alloc((size_t)2 * B_ * 4);
  float* rowsum  = (float*)alloc((size_t)2 * B_ * 4);
  u16* ball = (u16*)alloc((size_t)N_ * D_ * 2);

  size_t avail = ws_size > off ? ws_size - off : 0;
  int SR = (int)(avail / ((size_t)N_ * 2));
  SR &= ~127;
  if (SR > B_) SR = B_;
  if (SR < 128) SR = 128;
  u16* slab = (u16*)(ws + off);

  // zero the per-row expsum accumulators (deterministic per call)
  hipMemsetAsync(rowsum, 0, (size_t)2 * B_ * 4, stream);

  k_normalize<<<dim3(2 * B_), dim3(64), 0, stream>>>(
      rgb_feat, ir_feat, epoch, zrA, ziA, zrU, ziU);

  for (int dir = 0; dir < 2; ++dir) {
    const u16*   Amat   = (dir == 0) ? zrA : ziA;
    const u16*   zOther = (dir == 0) ? ziU : zrU;
    const float* queue  = (dir == 0) ? ir_q : rgb_q;
    float* diagD = diag    + dir * B_;
    float* lossD = rowloss + dir * B_;
    float* rsumD = rowsum  + dir * B_;

    k_build_ball<<<dim3((unsigned)((size_t)N_ * D_ / 8 / 256)), dim3(256), 0, stream>>>(
        zOther, queue, ball);

    for (int r0 = 0; r0 < B_; r0 += SR) {
      int cur = (B_ - r0) < SR ? (B_ - r0) : SR;
      int mtiles = cur / 128;
      int nwg = (N_ / 128) * mtiles;   // 520 * mtiles, divisible by 8
      k_gemm<<<dim3(nwg), dim3(256), 0, stream>>>(
          Amat, ball, slab, diagD, rsumD, r0, mtiles);
      k_select<<<dim3(cur), dim3(256), 0, stream>>>(slab, diagD, rsumD, lossD, r0);
    }
  }

  k_final<<<dim3(1), dim3(256), 0, stream>>>(rowloss, (float*)d_out);
}

// Round 22
// 297.546 us; speedup vs baseline: 1.3297x; 1.3297x over previous
//
#include <hip/hip_runtime.h>
#include <hip/hip_bf16.h>

// ---- problem constants ----
#define B_    1024
#define D_    384
#define Q_    65536
#define N_    66560            // B_ + Q_
#define TOPK_ 128

#define NBIN_ 4096             // histogram bins = key >> 4
#define CAP_  2048             // fallback candidate cap
#define SRANK_ 24              // sample rank (of 4096) for fine-bin threshold
#define SLOTS_ 17              // 16 real + 1 trash slot per thread

typedef __bf16 bf16x8 __attribute__((ext_vector_type(8)));
typedef float  f32x4  __attribute__((ext_vector_type(4)));
typedef unsigned short u16;
typedef u16 u16x8 __attribute__((ext_vector_type(8)));

// RNE float -> bf16 (bit-level)
__device__ __forceinline__ unsigned short f2bf(float x) {
  unsigned int u = __float_as_uint(x);
  unsigned int r = (u + 0x7fffu + ((u >> 16) & 1u)) >> 16;
  return (unsigned short)r;
}

__device__ __forceinline__ void gld_lds16(const void* g, void* l) {
  __builtin_amdgcn_global_load_lds(
      (__attribute__((address_space(1))) void*)(g),
      (__attribute__((address_space(3))) void*)(l), 16, 0, 0);
}

__device__ __forceinline__ void wait_vmcnt(int n) {
  switch (n) {
    case 4:  asm volatile("s_waitcnt vmcnt(4)"  ::: "memory"); break;
    default: asm volatile("s_waitcnt vmcnt(0)"  ::: "memory"); break;
  }
}

// monotone key <-> bf16 bits
__device__ __forceinline__ unsigned int bf2key(unsigned int u) {
  return u ^ ((u & 0x8000u) ? 0xFFFFu : 0x8000u);
}
__device__ __forceinline__ float key2val(unsigned int k) {
  unsigned int u = (k & 0x8000u) ? (k ^ 0x8000u) : (~k & 0xFFFFu);
  return __uint_as_float(u << 16);
}

// ---------------------------------------------------------------------------
// Normalize rgb/ir feats -> bf16 z (Ball role) and bf16 z/temp (A role).
// ---------------------------------------------------------------------------
__global__ __launch_bounds__(64) void k_normalize(
    const float* __restrict__ rgb, const float* __restrict__ ir,
    const int* __restrict__ ep,
    u16* __restrict__ zrA, u16* __restrict__ ziA,
    u16* __restrict__ zrU, u16* __restrict__ ziU)
{
  int r = blockIdx.x & (B_ - 1);
  bool isIr = blockIdx.x >= B_;
  const float* src = (isIr ? ir : rgb) + (size_t)r * D_;
  u16* dA = (isIr ? ziA : zrA) + (size_t)r * D_;
  u16* dU = (isIr ? ziU : zrU) + (size_t)r * D_;
  int t = threadIdx.x;
  float x[6]; float ss = 0.f;
  #pragma unroll
  for (int k = 0; k < 6; ++k) { x[k] = src[t + 64*k]; ss += x[k]*x[k]; }
  #pragma unroll
  for (int off = 32; off > 0; off >>= 1) ss += __shfl_down(ss, off);
  ss = __shfl(ss, 0);
  float inv = 1.0f / fmaxf(sqrtf(ss), 1e-12f);

  int e = ep[0];
  float temp;
  if (e >= 10) temp = 0.05f;
  else {
    float p = (float)e * 0.1f;
    temp = 0.05f + 0.075f * (1.0f + cosf(3.14159265358979323846f * p));
  }
  float itemp = 1.0f / temp;

  #pragma unroll
  for (int k = 0; k < 6; ++k) {
    float z = x[k] * inv;
    dU[t + 64*k] = f2bf(z);
    dA[t + 64*k] = f2bf(z * itemp);
  }
}

// ---------------------------------------------------------------------------
// Build Ball bf16 [N_][D_] = [z_other (bf16 copy) ; queue (f32->bf16)]
// ---------------------------------------------------------------------------
__global__ __launch_bounds__(256) void k_build_ball(
    const u16* __restrict__ zU, const float* __restrict__ queue,
    u16* __restrict__ ball)
{
  size_t i = ((size_t)blockIdx.x * 256 + threadIdx.x) * 8;
  const size_t zElems = (size_t)B_ * D_;
  if (i < zElems) {
    *(uint4*)(ball + i) = *(const uint4*)(zU + i);
  } else {
    const float* q = queue + (i - zElems);
    float4 a = *(const float4*)q;
    float4 b = *(const float4*)(q + 4);
    u16x8 o;
    o[0] = f2bf(a.x); o[1] = f2bf(a.y); o[2] = f2bf(a.z); o[3] = f2bf(a.w);
    o[4] = f2bf(b.x); o[5] = f2bf(b.y); o[6] = f2bf(b.z); o[7] = f2bf(b.w);
    *(u16x8*)(ball + i) = o;
  }
}

// ---------------------------------------------------------------------------
// bf16 MFMA GEMM -> bf16 logits slab (r15 config, best: 78us).
// 128x128 tile, 4 waves. T1 XCD swizzle. T2 XOR swizzle (64B rows).
// BK=32, 12 steps, 3 x 16KB LDS buffers (48KB -> 3 blocks/CU), depth-2
// counted vmcnt(4), single barrier per step.
// ---------------------------------------------------------------------------
#define BK_ 32
#define NSTEP_ 12              // D_ / BK_
__global__ __launch_bounds__(256, 3) void k_gemm(
    const u16* __restrict__ A,     // [B_][D_] scaled bf16
    const u16* __restrict__ ball,  // [N_][D_] bf16
    u16* __restrict__ C,           // [SR][N_] bf16 logits
    float* __restrict__ diag,      // [B_]
    int r0, int mtiles)
{
  __shared__ __align__(16) unsigned char smem[49152];  // 3 x (8KB A + 8KB B)
  u16* Ct = (u16*)smem;          // epilogue bounce [128][136] (34.8 KB)

  int bid = blockIdx.x;
  int nwg = gridDim.x;
  int cpx = nwg >> 3;
  int wgid = (bid & 7) * cpx + (bid >> 3);
  int nt = wgid / mtiles;
  int mt = wgid - nt * mtiles;

  const int tid  = threadIdx.x;
  const int wave = tid >> 6, lane = tid & 63;
  const int wm = wave >> 1, wn = wave & 1;
  const int mbase = mt * 128;
  const int nbase = nt * 128;
  const u16* Ab = A    + (size_t)(r0 + mbase) * D_;
  const u16* Bb = ball + (size_t)nbase * D_;

  auto As = [&](int t) -> u16* { return (u16*)(smem + (t % 3) * 16384); };
  auto Bs = [&](int t) -> u16* { return (u16*)(smem + (t % 3) * 16384 + 8192); };
  auto stage = [&](int t) {
    const int ks = t * BK_;
    #pragma unroll
    for (int i = 0; i < 2; ++i) {
      int f = i * 256 + tid;
      int rr = f >> 2, cc = f & 3;
      int koff = (((cc * 16) ^ (((rr >> 1) & 3) << 4)) >> 1);
      gld_lds16(Ab + (size_t)rr * D_ + ks + koff, As(t) + (size_t)f * 8);
      gld_lds16(Bb + (size_t)rr * D_ + ks + koff, Bs(t) + (size_t)f * 8);
    }
  };

  f32x4 acc[4][4];
  #pragma unroll
  for (int m = 0; m < 4; ++m)
    #pragma unroll
    for (int n = 0; n < 4; ++n)
      #pragma unroll
      for (int r = 0; r < 4; ++r) acc[m][n][r] = 0.0f;

  const int lr = lane & 15;
  const int kb = (lane >> 4) * 16;   // byte column within the 64B row

  stage(0); stage(1);                // 8 loads/thread in flight

  #pragma unroll
  for (int t = 0; t < NSTEP_; ++t) {
    wait_vmcnt(t < NSTEP_ - 1 ? 4 : 0);      // tile t landed (t+1 in flight)
    __builtin_amdgcn_s_barrier();            // tile t ready AND all waves done
    __builtin_amdgcn_sched_barrier(0);       //   reading tile t-1

    const u16* Ac = As(t);
    const u16* Bc = Bs(t);
    bf16x8 af[4], bq[4];
    #pragma unroll
    for (int m = 0; m < 4; ++m) {
      int row = wm*64 + m*16 + lr;
      af[m] = *(const bf16x8*)((const char*)Ac + row * 64 + (kb ^ (((row >> 1) & 3) << 4)));
    }
    #pragma unroll
    for (int n = 0; n < 4; ++n) {
      int row = wn*64 + n*16 + lr;
      bq[n] = *(const bf16x8*)((const char*)Bc + row * 64 + (kb ^ (((row >> 1) & 3) << 4)));
    }
    if (t + 2 < NSTEP_) stage(t + 2);        // overwrites buffer (t-1)%3: safe

    #pragma unroll
    for (int m = 0; m < 4; ++m)
      #pragma unroll
      for (int n = 0; n < 4; ++n)
        acc[m][n] = __builtin_amdgcn_mfma_f32_16x16x32_bf16(af[m], bq[n], acc[m][n], 0, 0, 0);

    asm volatile("s_waitcnt lgkmcnt(0)" ::: "memory");  // my ds_reads done
    __builtin_amdgcn_sched_barrier(0);
  }
  __syncthreads();                           // all waves done before smem reuse

  const int rowq = (lane >> 4) * 4;
  #pragma unroll
  for (int m = 0; m < 4; ++m) {
    #pragma unroll
    for (int n = 0; n < 4; ++n) {
      int lcol = wn*64 + n*16 + lr;
      int gcol = nbase + lcol;
      #pragma unroll
      for (int r = 0; r < 4; ++r) {
        int lrow = wm*64 + m*16 + rowq + r;
        float x = acc[m][n][r];
        int grow = r0 + mbase + lrow;
        if (gcol == grow) { diag[grow] = x; x = -60.0f; }
        Ct[lrow * 136 + lcol] = f2bf(x);
      }
    }
  }
  __syncthreads();

  int rrow = tid >> 4;             // 0..15
  int cchunk = (tid & 15) * 8;     // u16 index within row
  #pragma unroll
  for (int pass = 0; pass < 8; ++pass) {
    int row = pass * 16 + rrow;
    u16x8 v = *(const u16x8*)(Ct + row * 136 + cchunk);
    *(u16x8*)(C + (size_t)(mbase + row) * N_ + nbase + cchunk) = v;
  }
}

// ---------------------------------------------------------------------------
// Per-row exact top-128 + exp-sum + loss. SINGLE sweep, NO per-element
// histogram: hot loop = load + expf + sum + branchless slot-write + count.
// Monotonicity: all collected keys (bin >= tfine) > all non-collected
// (bin < tfine), so if total collected >= 128 (and no slot overflow) the
// global top-128 is inside the slots. Boundary resolved exactly by
// histogramming only the ~850 collected keys. Fallback: full 2-sweep.
// ---------------------------------------------------------------------------
__global__ __launch_bounds__(256) void k_select(
    const u16* __restrict__ C, const float* __restrict__ diag,
    float* __restrict__ rowloss, int r0)
{
  __shared__ unsigned int hist[NBIN_];          // 16 KB
  __shared__ u16 keyslots[256 * SLOTS_];        // 8.5 KB
  __shared__ float vals[CAP_];                  // 8 KB (fallback only)
  __shared__ float fred[256];
  __shared__ unsigned int csum[256];
  __shared__ int lcnt[256];
  __shared__ unsigned int subhist[16];
  __shared__ float sh_d2;
  __shared__ int shv[4];                        // 0:bstar 1:above 2:cnt 3:tfine

  const int t = threadIdx.x;
  const int grow = r0 + blockIdx.x;
  const u16x8* p = (const u16x8*)(C + (size_t)blockIdx.x * N_);

  uint4* h4 = (uint4*)hist;
  #pragma unroll
  for (int i = 0; i < 4; ++i) h4[i * 256 + t] = make_uint4(0,0,0,0);
  if (t < 16) subhist[t] = 0;
  if (t == 0) { shv[2] = 0; sh_d2 = 0.f; }
  __syncthreads();

  // ---- sample phase: 4096 values -> fine histogram -> tfine ----
  {
    u16x8 s0 = p[t * 32];
    u16x8 s1 = p[t * 32 + 16];
    #pragma unroll
    for (int e = 0; e < 8; ++e) {
      atomicAdd(&hist[bf2key((unsigned int)(unsigned short)s0[e]) >> 4], 1u);
      atomicAdd(&hist[bf2key((unsigned int)(unsigned short)s1[e]) >> 4], 1u);
    }
  }
  __syncthreads();
  {
    unsigned int S = 0;
    #pragma unroll
    for (int i = 0; i < 16; ++i) S += hist[t * 16 + i];
    csum[t] = S;
    __syncthreads();
    unsigned int a = S;
    #pragma unroll
    for (int s = 1; s < 256; s <<= 1) {
      unsigned int add = (t + s < 256) ? csum[t + s] : 0u;
      __syncthreads();
      a += add; csum[t] = a;
      __syncthreads();
    }
    int above = (t < 255) ? (int)csum[t + 1] : 0;
    if (above < SRANK_ && above + (int)S >= SRANK_) {
      int cum = above;
      #pragma unroll 1
      for (int i = 15; i >= 0; --i) {
        int c = (int)hist[t * 16 + i];
        if (cum + c >= SRANK_) { shv[3] = t * 16 + i; break; }
        cum += c;
      }
    }
  }
  __syncthreads();
  const unsigned int tfine = (unsigned int)shv[3];
  #pragma unroll
  for (int i = 0; i < 4; ++i) h4[i * 256 + t] = make_uint4(0,0,0,0);
  __syncthreads();

  // ---- main sweep: expsum + branchless slot collect (NO histogram) ----
  u16* myslots = keyslots + t * SLOTS_;
  int lc = 0;
  float es0 = 0.f, es1 = 0.f;
  #pragma unroll 1
  for (int base = 0; base < 8192; base += 2048) {
    u16x8 v[8];
    #pragma unroll
    for (int j = 0; j < 8; ++j) v[j] = p[base + j * 256 + t];
    #pragma unroll
    for (int j = 0; j < 8; ++j) {
      #pragma unroll
      for (int e = 0; e < 8; ++e) {
        unsigned int u = (unsigned int)(unsigned short)v[j][e];
        unsigned int k = bf2key(u);
        float ex = __expf(__uint_as_float(u << 16));
        if (j & 1) es1 += ex; else es0 += ex;
        myslots[lc < 16 ? lc : 16] = (u16)k;     // unconditional write
        lc += ((k >> 4) >= tfine);               // branchless count
      }
    }
  }
  if (t < 128) {                         // tail: chunks 8192..8319
    u16x8 v = p[8192 + t];
    #pragma unroll
    for (int e = 0; e < 8; ++e) {
      unsigned int u = (unsigned int)(unsigned short)v[e];
      unsigned int k = bf2key(u);
      es0 += __expf(__uint_as_float(u << 16));
      myslots[lc < 16 ? lc : 16] = (u16)k;
      lc += ((k >> 4) >= tfine);
    }
  }
  float esum = es0 + es1;
  lcnt[t] = lc;
  __syncthreads();

  // ---- total candidate count + overflow check ----
  {
    unsigned int a = (unsigned int)lcnt[t];
    csum[t] = a;
    __syncthreads();
    #pragma unroll
    for (int s = 128; s > 0; s >>= 1) {
      unsigned int add = (t < s) ? csum[t + s] : 0u;
      __syncthreads();
      if (t < s) csum[t] = csum[t] + add;
      __syncthreads();
    }
  }
  const int cntTot = (int)csum[0];
  int ok_lc = __syncthreads_and(lc <= 16);

  float delta = 0.f;
  if (ok_lc && cntTot >= TOPK_) {
    // ---- fast path: histogram ONLY the candidates (~850 atomics) ----
    #pragma unroll 1
    for (int i = t; i < 256 * 16; i += 256) {
      int ts = i >> 4, sl = i & 15;
      int c = lcnt[ts]; c = c < 16 ? c : 16;
      if (sl < c)
        atomicAdd(&hist[(unsigned int)keyslots[ts * SLOTS_ + sl] >> 4], 1u);
    }
    __syncthreads();
    // exact chunk sums + suffix scan over candidate histogram
    unsigned int S = 0;
    #pragma unroll
    for (int i = 0; i < 16; ++i) S += hist[t * 16 + i];
    csum[t] = S;
    __syncthreads();
    unsigned int a = S;
    #pragma unroll
    for (int s = 1; s < 256; s <<= 1) {
      unsigned int add = (t + s < 256) ? csum[t + s] : 0u;
      __syncthreads();
      a += add; csum[t] = a;
      __syncthreads();
    }
    int above_chunk = (t < 255) ? (int)csum[t + 1] : 0;
    if (above_chunk < TOPK_ && above_chunk + (int)S >= TOPK_) {
      int cum = above_chunk;
      #pragma unroll 1
      for (int i = 15; i >= 0; --i) {
        int c = (int)hist[t * 16 + i];
        if (cum + c >= TOPK_) { shv[0] = t * 16 + i; shv[1] = cum; break; }
        cum += c;
      }
    }
    __syncthreads();
    const unsigned int bstar = (unsigned int)shv[0];
    const int need0 = TOPK_ - shv[1];
    // walk slots: above-bstar direct, boundary bin -> sub-key histogram
    #pragma unroll 1
    for (int i = t; i < 256 * 16; i += 256) {
      int ts = i >> 4, sl = i & 15;
      int c = lcnt[ts]; c = c < 16 ? c : 16;
      if (sl < c) {
        unsigned int k = (unsigned int)keyslots[ts * SLOTS_ + sl];
        unsigned int bin = k >> 4;
        if (bin > bstar) {
          float v = key2val(k);
          delta += __expf(2.f * v) - __expf(v);
        } else if (bin == bstar) {
          atomicAdd(&subhist[k & 15], 1u);
        }
      }
    }
    __syncthreads();
    if (t == 0) {
      int need = need0; float d2 = 0.f;
      #pragma unroll 1
      for (int sk = 15; sk >= 0 && need > 0; --sk) {
        int c = (int)subhist[sk];
        if (c > 0) {
          int take = c < need ? c : need;
          float v = key2val((bstar << 4) | (unsigned int)sk);
          d2 += (float)take * (__expf(2.f * v) - __expf(v));
          need -= take;
        }
      }
      sh_d2 = d2;
    }
  } else {
    // ---- exact fallback: full 2-sweep (hist sweep + collect sweep) ----
    #pragma unroll 1
    for (int base = 0; base < 8192; base += 2048) {
      u16x8 v[8];
      #pragma unroll
      for (int j = 0; j < 8; ++j) v[j] = p[base + j * 256 + t];
      #pragma unroll
      for (int j = 0; j < 8; ++j)
        #pragma unroll
        for (int e = 0; e < 8; ++e)
          atomicAdd(&hist[bf2key((unsigned int)(unsigned short)v[j][e]) >> 4], 1u);
    }
    if (t < 128) {
      u16x8 v = p[8192 + t];
      #pragma unroll
      for (int e = 0; e < 8; ++e)
        atomicAdd(&hist[bf2key((unsigned int)(unsigned short)v[e]) >> 4], 1u);
    }
    __syncthreads();
    unsigned int S = 0;
    #pragma unroll
    for (int i = 0; i < 16; ++i) S += hist[t * 16 + i];
    csum[t] = S;
    __syncthreads();
    unsigned int a = S;
    #pragma unroll
    for (int s = 1; s < 256; s <<= 1) {
      unsigned int add = (t + s < 256) ? csum[t + s] : 0u;
      __syncthreads();
      a += add; csum[t] = a;
      __syncthreads();
    }
    int above_chunk = (t < 255) ? (int)csum[t + 1] : 0;
    if (above_chunk < TOPK_ && above_chunk + (int)S >= TOPK_) {
      int cum = above_chunk;
      #pragma unroll 1
      for (int i = 15; i >= 0; --i) {
        int c = (int)hist[t * 16 + i];
        if (cum + c >= TOPK_) { shv[0] = t * 16 + i; shv[1] = cum; break; }
        cum += c;
      }
    }
    __syncthreads();
    const unsigned int bstar = (unsigned int)shv[0];
    const int need0 = TOPK_ - shv[1];
    #pragma unroll 1
    for (int base = 0; base < 8192; base += 2048) {
      u16x8 v[8];
      #pragma unroll
      for (int j = 0; j < 8; ++j) v[j] = p[base + j * 256 + t];
      #pragma unroll
      for (int j = 0; j < 8; ++j) {
        #pragma unroll
        for (int e = 0; e < 8; ++e) {
          unsigned int u = (unsigned int)(unsigned short)v[j][e];
          unsigned int bin = bf2key(u) >> 4;
          if (bin >= bstar) {
            float val = __uint_as_float(u << 16);
            if (bin > bstar) delta += __expf(2.f * val) - __expf(val);
            else { int s = atomicAdd(&shv[2], 1); if (s < CAP_) vals[s] = val; }
          }
        }
      }
    }
    if (t < 128) {
      u16x8 v = p[8192 + t];
      #pragma unroll
      for (int e = 0; e < 8; ++e) {
        unsigned int u = (unsigned int)(unsigned short)v[e];
        unsigned int bin = bf2key(u) >> 4;
        if (bin >= bstar) {
          float val = __uint_as_float(u << 16);
          if (bin > bstar) delta += __expf(2.f * val) - __expf(val);
          else { int s = atomicAdd(&shv[2], 1); if (s < CAP_) vals[s] = val; }
        }
      }
    }
    __syncthreads();
    int C2 = shv[2] < CAP_ ? shv[2] : CAP_;
    for (int i = t; i < C2; i += 256) {
      float v = vals[i];
      int g = 0;
      for (int k = 0; k < C2; ++k)
        g += (vals[k] > v) || (vals[k] == v && k < i);
      if (g < need0) delta += __expf(2.f * v) - __expf(v);
    }
  }

  fred[t] = esum + delta;
  __syncthreads();
  #pragma unroll
  for (int s = 128; s > 0; s >>= 1) { if (t < s) fred[t] += fred[t + s]; __syncthreads(); }

  if (t == 0) {
    float d = diag[grow];
    rowloss[grow] = logf(fred[0] + sh_d2 + __expf(d)) - d;
  }
}

__global__ __launch_bounds__(256) void k_final(
    const float* __restrict__ rowloss, float* __restrict__ out)
{
  __shared__ float red[256];
  int t = threadIdx.x;
  float s = 0.f;
  for (int i = t; i < 2 * B_; i += 256) s += rowloss[i];
  red[t] = s;
  __syncthreads();
  for (int k = 128; k > 0; k >>= 1) { if (t < k) red[t] += red[t + k]; __syncthreads(); }
  if (t == 0) out[0] = red[0] * (1.0f / (2.0f * B_));
}

// ---------------------------------------------------------------------------
extern "C" void kernel_launch(void* const* d_in, const int* in_sizes, int n_in,
                              void* d_out, int out_size, void* d_ws, size_t ws_size,
                              hipStream_t stream)
{
  const float* rgb_feat = (const float*)d_in[0];
  const float* ir_feat  = (const float*)d_in[1];
  const float* rgb_q    = (const float*)d_in[2];
  const float* ir_q     = (const float*)d_in[3];
  const int*   epoch    = (const int*)d_in[4];

  char* ws = (char*)d_ws;
  size_t off = 0;
  auto alloc = [&](size_t bytes) -> char* {
    char* p = ws + off;
    off = (off + bytes + 255) & ~(size_t)255;
    return p;
  };

  u16* zrA = (u16*)alloc((size_t)B_ * D_ * 2);
  u16* ziA = (u16*)alloc((size_t)B_ * D_ * 2);
  u16* zrU = (u16*)alloc((size_t)B_ * D_ * 2);
  u16* ziU = (u16*)alloc((size_t)B_ * D_ * 2);
  float* diag    = (float*)alloc((size_t)2 * B_ * 4);
  float* rowloss = (float*)alloc((size_t)2 * B_ * 4);
  u16* ball = (u16*)alloc((size_t)N_ * D_ * 2);

  size_t avail = ws_size > off ? ws_size - off : 0;
  int SR = (int)(avail / ((size_t)N_ * 2));
  SR &= ~127;
  if (SR > B_) SR = B_;
  if (SR < 128) SR = 128;
  u16* slab = (u16*)(ws + off);

  k_normalize<<<dim3(2 * B_), dim3(64), 0, stream>>>(
      rgb_feat, ir_feat, epoch, zrA, ziA, zrU, ziU);

  for (int dir = 0; dir < 2; ++dir) {
    const u16*   Amat   = (dir == 0) ? zrA : ziA;
    const u16*   zOther = (dir == 0) ? ziU : zrU;
    const float* queue  = (dir == 0) ? ir_q : rgb_q;
    float* diagD = diag    + dir * B_;
    float* lossD = rowloss + dir * B_;

    k_build_ball<<<dim3((unsigned)((size_t)N_ * D_ / 8 / 256)), dim3(256), 0, stream>>>(
        zOther, queue, ball);

    for (int r0 = 0; r0 < B_; r0 += SR) {
      int cur = (B_ - r0) < SR ? (B_ - r0) : SR;
      int mtiles = cur / 128;
      int nwg = (N_ / 128) * mtiles;   // 520 * mtiles, divisible by 8
      k_gemm<<<dim3(nwg), dim3(256), 0, stream>>>(
          Amat, ball, slab, diagD, r0, mtiles);
      k_select<<<dim3(cur), dim3(256), 0, stream>>>(slab, diagD, lossD, r0);
    }
  }

  k_final<<<dim3(1), dim3(256), 0, stream>>>(rowloss, (float*)d_out);
}